// Round 6
// baseline (88.480 us; speedup 1.0000x reference)
//
#include <hip/hip_runtime.h>
#include <hip/hip_bf16.h>
#include <stdint.h>

typedef int i32x4 __attribute__((ext_vector_type(4)));

constexpr int IN_F = 1024;
constexpr int OUT_F = 1024;
constexpr int M_TOT = 8 * 4096;   // 32768 tokens
constexpr int K_TOT = IN_F;
constexpr int N_TOT = OUT_F;

// ---------------- kernel 1: per-token int8 fake-quant -> int8 q ----------------
__global__ __launch_bounds__(256) void quant_kernel(
    const float* __restrict__ x,
    const float* __restrict__ wscale,
    int8_t* __restrict__ q,            // [M_TOT][K_TOT] int8
    float* __restrict__ inv_row)       // [M_TOT]  (= a/127 * weight_scale)
{
    const int row = blockIdx.x;
    const int t = threadIdx.x;
    const float4 v = reinterpret_cast<const float4*>(x + (size_t)row * IN_F)[t];
    float m = fmaxf(fmaxf(fabsf(v.x), fabsf(v.y)), fmaxf(fabsf(v.z), fabsf(v.w)));
    #pragma unroll
    for (int off = 32; off > 0; off >>= 1)
        m = fmaxf(m, __shfl_xor(m, off));
    __shared__ float smax[4];
    if ((t & 63) == 0) smax[t >> 6] = m;
    __syncthreads();
    m = fmaxf(fmaxf(smax[0], smax[1]), fmaxf(smax[2], smax[3]));
    const float a = fmaxf(m, 1e-5f);
    const float as = 127.0f / a;

    char4 o;
    o.x = (char)(int)fminf(fmaxf(rintf(v.x * as), -128.0f), 127.0f);
    o.y = (char)(int)fminf(fmaxf(rintf(v.y * as), -128.0f), 127.0f);
    o.z = (char)(int)fminf(fmaxf(rintf(v.z * as), -128.0f), 127.0f);
    o.w = (char)(int)fminf(fmaxf(rintf(v.w * as), -128.0f), 127.0f);
    reinterpret_cast<char4*>(q + (size_t)row * IN_F)[t] = o;
    if (t == 0) inv_row[row] = (a / 127.0f) * wscale[0];
}

// ---------------- kernel 2: unpack ternary weights (bit-plane permuted) -> int8 ----------------
__global__ __launch_bounds__(256) void unpack_kernel(
    const int* __restrict__ packed,
    int8_t* __restrict__ wt)           // [OUT_F][IN_F] int8 in {-1,0,1} (B^T layout)
{
    const int o = blockIdx.x;
    const int k0 = threadIdx.x * 4;
    const int sh = (o >> 8) * 2;
    const int pbase = ((o & 255) << 10) + k0;
    const int4 pw = *reinterpret_cast<const int4*>(packed + pbase);
    char4 r;
    r.x = (char)(((pw.x >> sh) & 3) - 1);
    r.y = (char)(((pw.y >> sh) & 3) - 1);
    r.z = (char)(((pw.z >> sh) & 3) - 1);
    r.w = (char)(((pw.w >> sh) & 3) - 1);
    *reinterpret_cast<char4*>(wt + (size_t)o * IN_F + k0) = r;
}

// ---------------- kernel 3: int8 MFMA GEMM, BM=256 x BN=128, BK=128, 4-phase ----------------
// mfma_i32_16x16x64_i8. 8 waves (4M x 2N), per-wave 64x64 output. Grid 1024 -> 4
// pipelined block-rounds/CU (hides C-write). LDS 96 KiB = [buf2][region3][128x128 i8]:
// region 0 = A rows with (g&63)<32 (local = (g>>6)*32 + (g&31)), region 1 = complement,
// region 2 = B. Per K-tile 4 phases, each {<=8 ds_read_b128 || 1 region stage -> bar ->
// lgkm+sched_barrier -> setprio + 8 MFMA -> bar}; frags register-held (each LDS elem
// read once/K-tile). Counted waits: vmcnt(4)@P1-end (certifies A-R1(T) for P2),
// vmcnt(2)@P3-end (certifies B+A-R0(T+1) for next P0). Never 0 mid-loop.
// T2 swizzle: linear LDS dest, inverse-swizzled global src, swizzled ds_read (2-way free).
constexpr int BM = 256, BN = 128, BK = 128;
constexpr int NT = K_TOT / BK;   // 8

__global__ __launch_bounds__(512, 2) void gemm_kernel(
    const int8_t* __restrict__ qa,     // [M_TOT][K_TOT] int8
    const int8_t* __restrict__ wb,     // [N_TOT][K_TOT] int8
    const float* __restrict__ inv_row,
    const float* __restrict__ bias,
    float* __restrict__ out)
{
    // XCD-aware swizzle: nwg = 1024, divisible by 8 -> bijective simple remap
    int bid = blockIdx.x;
    bid = (bid & 7) * ((int)gridDim.x >> 3) + (bid >> 3);
    const int tm = bid >> 3;            // 0..127
    const int tn = bid & 7;             // 0..7

    const int tid = threadIdx.x;
    const int lane = tid & 63;
    const int wid = tid >> 6;           // 0..7
    const int wr = wid >> 1;            // 0..3 (M quarter: rows wr*64..)
    const int wc = wid & 1;             // 0..1 (N half: cols wc*64..)

    __shared__ int8_t lds[2][3][128 * 128];  // [buf][region] 16 KiB each = 96 KiB

    const int rowA0 = tm * BM;
    const int rowB0 = tn * BN;
    const int frow = lane & 15;
    const int fq = lane >> 4;           // 0..3

    i32x4 acc[4][4] = {};

    // stage one 16 KiB region: 2 global_load_lds per thread
    auto stage = [&](int buf, int reg, int kt) {
        #pragma unroll
        for (int j = 0; j < 2; ++j) {
            const int c = j * 512 + tid;          // chunk 0..1023 (16B each)
            const int rl = c >> 3, cc = c & 7;
            const int scc = cc ^ (rl & 7);        // inverse swizzle on global src
            const int8_t* src;
            if (reg == 2)
                src = wb + (size_t)(rowB0 + rl) * K_TOT + kt * BK + scc * 16;
            else
                src = qa + (size_t)(rowA0 + (rl >> 5) * 64 + reg * 32 + (rl & 31)) * K_TOT
                         + kt * BK + scc * 16;
            __builtin_amdgcn_global_load_lds(
                (const __attribute__((address_space(1))) void*)src,
                (__attribute__((address_space(3))) void*)&lds[buf][reg][c * 16],
                16, 0, 0);
        }
    };

    // A frag: global row g = wr*64 + mf*16 + frow -> reg = mf>>1, local = wr*32 + (mf&1)*16 + frow
    auto ldA = [&](int buf, int mf, int ks) -> i32x4 {
        const int local = wr * 32 + (mf & 1) * 16 + frow;
        const int ch = (ks * 4 + fq) ^ (local & 7);
        return *reinterpret_cast<const i32x4*>(&lds[buf][mf >> 1][local * 128 + ch * 16]);
    };
    // B frag: col n = wc*64 + (nf>>1)*32 + (nf&1)*16 + frow, region 2
    auto ldB = [&](int buf, int nf, int ks) -> i32x4 {
        const int local = wc * 64 + (nf >> 1) * 32 + (nf & 1) * 16 + frow;
        const int ch = (ks * 4 + fq) ^ (local & 7);
        return *reinterpret_cast<const i32x4*>(&lds[buf][2][local * 128 + ch * 16]);
    };

    // prologue: stage tile 0 fully (6 loads), drain, barrier
    stage(0, 2, 0); stage(0, 0, 0); stage(0, 1, 0);
    asm volatile("s_waitcnt vmcnt(0)" ::: "memory");
    __builtin_amdgcn_s_barrier();

    for (int T = 0; T < NT; ++T) {
        const int cur = T & 1, nxt = cur ^ 1;
        const bool st = (T + 1 < NT);
        i32x4 aF[2][2], bF0[2][2], bF1[2][2];

        // ---- P0: read A m01 (4) + B n01 (4); stage B(T+1); MFMA q(0,0)
        #pragma unroll
        for (int mf = 0; mf < 2; ++mf)
            #pragma unroll
            for (int ks = 0; ks < 2; ++ks)
                aF[mf][ks] = ldA(cur, mf, ks);
        #pragma unroll
        for (int nf = 0; nf < 2; ++nf)
            #pragma unroll
            for (int ks = 0; ks < 2; ++ks)
                bF0[nf][ks] = ldB(cur, nf, ks);
        if (st) stage(nxt, 2, T + 1);
        __builtin_amdgcn_s_barrier();
        asm volatile("s_waitcnt lgkmcnt(0)" ::: "memory");
        __builtin_amdgcn_sched_barrier(0);
        __builtin_amdgcn_s_setprio(1);
        #pragma unroll
        for (int mf = 0; mf < 2; ++mf)
            #pragma unroll
            for (int nf = 0; nf < 2; ++nf)
                #pragma unroll
                for (int ks = 0; ks < 2; ++ks)
                    acc[mf][nf] = __builtin_amdgcn_mfma_i32_16x16x64_i8(
                        aF[mf][ks], bF0[nf][ks], acc[mf][nf], 0, 0, 0);
        __builtin_amdgcn_s_setprio(0);
        __builtin_amdgcn_s_barrier();

        // ---- P1: read B n23 (4); stage A-R0(T+1); MFMA q(0,1)
        #pragma unroll
        for (int nf = 0; nf < 2; ++nf)
            #pragma unroll
            for (int ks = 0; ks < 2; ++ks)
                bF1[nf][ks] = ldB(cur, 2 + nf, ks);
        if (st) stage(nxt, 0, T + 1);
        __builtin_amdgcn_s_barrier();
        asm volatile("s_waitcnt lgkmcnt(0)" ::: "memory");
        __builtin_amdgcn_sched_barrier(0);
        __builtin_amdgcn_s_setprio(1);
        #pragma unroll
        for (int mf = 0; mf < 2; ++mf)
            #pragma unroll
            for (int nf = 0; nf < 2; ++nf)
                #pragma unroll
                for (int ks = 0; ks < 2; ++ks)
                    acc[mf][2 + nf] = __builtin_amdgcn_mfma_i32_16x16x64_i8(
                        aF[mf][ks], bF1[nf][ks], acc[mf][2 + nf], 0, 0, 0);
        __builtin_amdgcn_s_setprio(0);
        // certify A-R1(T) for P2 (oldest-2 of in-flight {A-R1(T), B(T+1), A-R0(T+1)})
        if (st) asm volatile("s_waitcnt vmcnt(4)" ::: "memory");
        else    asm volatile("s_waitcnt vmcnt(0)" ::: "memory");
        __builtin_amdgcn_s_barrier();

        // ---- P2: read A m23 (4); stage A-R1(T+1); MFMA q(1,1)
        #pragma unroll
        for (int mf = 0; mf < 2; ++mf)
            #pragma unroll
            for (int ks = 0; ks < 2; ++ks)
                aF[mf][ks] = ldA(cur, 2 + mf, ks);
        if (st) stage(nxt, 1, T + 1);
        __builtin_amdgcn_s_barrier();
        asm volatile("s_waitcnt lgkmcnt(0)" ::: "memory");
        __builtin_amdgcn_sched_barrier(0);
        __builtin_amdgcn_s_setprio(1);
        #pragma unroll
        for (int mf = 0; mf < 2; ++mf)
            #pragma unroll
            for (int nf = 0; nf < 2; ++nf)
                #pragma unroll
                for (int ks = 0; ks < 2; ++ks)
                    acc[2 + mf][2 + nf] = __builtin_amdgcn_mfma_i32_16x16x64_i8(
                        aF[mf][ks], bF1[nf][ks], acc[2 + mf][2 + nf], 0, 0, 0);
        __builtin_amdgcn_s_setprio(0);
        __builtin_amdgcn_s_barrier();

        // ---- P3: no reads/stage; MFMA q(1,0); counted vmcnt + barrier
        __builtin_amdgcn_s_setprio(1);
        #pragma unroll
        for (int mf = 0; mf < 2; ++mf)
            #pragma unroll
            for (int nf = 0; nf < 2; ++nf)
                #pragma unroll
                for (int ks = 0; ks < 2; ++ks)
                    acc[2 + mf][nf] = __builtin_amdgcn_mfma_i32_16x16x64_i8(
                        aF[mf][ks], bF0[nf][ks], acc[2 + mf][nf], 0, 0, 0);
        __builtin_amdgcn_s_setprio(0);
        if (st) {
            // certify B(T+1)+A-R0(T+1) for next P0; A-R1(T+1) stays in flight
            asm volatile("s_waitcnt vmcnt(2)" ::: "memory");
            __builtin_amdgcn_s_barrier();
        }
    }

    // epilogue: C/D 16x16 layout: col = lane&15, row = fq*4 + reg. acc exact in i32.
    #pragma unroll
    for (int mi = 0; mi < 4; ++mi) {
        #pragma unroll
        for (int j = 0; j < 4; ++j) {
            const int gm = rowA0 + wr * 64 + mi * 16 + fq * 4 + j;
            const float sc = inv_row[gm];
            #pragma unroll
            for (int nf = 0; nf < 4; ++nf) {
                const int gn = rowB0 + wc * 64 + (nf >> 1) * 32 + (nf & 1) * 16 + frow;
                out[(size_t)gm * N_TOT + gn] = (float)acc[mi][nf][j] * sc + bias[gn];
            }
        }
    }
}

extern "C" void kernel_launch(void* const* d_in, const int* in_sizes, int n_in,
                              void* d_out, int out_size, void* d_ws, size_t ws_size,
                              hipStream_t stream) {
    const float* x = (const float*)d_in[0];
    const int* packed = (const int*)d_in[1];
    const float* wscale = (const float*)d_in[2];
    const float* bias = (const float*)d_in[3];
    float* out = (float*)d_out;

    int8_t* q = (int8_t*)d_ws;                                          // 32 MiB
    int8_t* wt = (int8_t*)((char*)d_ws + (size_t)M_TOT * K_TOT);        // 1 MiB
    float* inv_row = (float*)((char*)d_ws + (size_t)M_TOT * K_TOT + (size_t)N_TOT * K_TOT);

    quant_kernel<<<M_TOT, 256, 0, stream>>>(x, wscale, q, inv_row);
    unpack_kernel<<<OUT_F, 256, 0, stream>>>(packed, wt);
    gemm_kernel<<<(M_TOT / BM) * (N_TOT / BN), 512, 0, stream>>>(q, wt, inv_row, bias, out);
}